// Round 3
// baseline (2055.045 us; speedup 1.0000x reference)
//
#include <hip/hip_runtime.h>

constexpr int Bn = 8, Nn = 1024, Cn = 768, Hn = 12, Dn = 64;

__device__ __forceinline__ unsigned toOrd(float f) {
  unsigned u = __float_as_uint(f);
  return (u & 0x80000000u) ? ~u : (u | 0x80000000u);
}

// ---------------- QKV GEMM: qkv = x @ qkv_w^T + b, scattered to q/k/v (B,H,N,d)
__global__ __launch_bounds__(256) void qkv_gemm(
    const float* __restrict__ X, const float* __restrict__ Wm,
    const float* __restrict__ bias,
    float* __restrict__ qb, float* __restrict__ kb, float* __restrict__ vb)
{
  constexpr int K = Cn, BK = 16, PAD = 68;
  __shared__ float As[BK][PAD];
  __shared__ float Bs[BK][PAD];
  int t = threadIdx.x;
  int tx = t & 15, ty = t >> 4;
  int mt = blockIdx.x & 127;        // 128 m-tiles
  int nt = blockIdx.x >> 7;         // 36 n-tiles
  int m0 = mt * 64, n0 = nt * 64;
  int lrow = t >> 2;                // 0..63
  int lk = (t & 3) * 4;             // 0,4,8,12
  const float* Arow = X + (size_t)(m0 + lrow) * K + lk;
  const float* Brow = Wm + (size_t)(n0 + lrow) * K + lk;
  float acc[4][4] = {};
  for (int k0 = 0; k0 < K; k0 += BK) {
    float4 a = *(const float4*)(Arow + k0);
    float4 b = *(const float4*)(Brow + k0);
    __syncthreads();
    As[lk+0][lrow] = a.x; As[lk+1][lrow] = a.y; As[lk+2][lrow] = a.z; As[lk+3][lrow] = a.w;
    Bs[lk+0][lrow] = b.x; Bs[lk+1][lrow] = b.y; Bs[lk+2][lrow] = b.z; Bs[lk+3][lrow] = b.w;
    __syncthreads();
#pragma unroll
    for (int kk = 0; kk < BK; ++kk) {
      float4 a4 = *(const float4*)(&As[kk][ty*4]);
      float4 b4 = *(const float4*)(&Bs[kk][tx*4]);
      float av[4] = {a4.x, a4.y, a4.z, a4.w};
      float bv[4] = {b4.x, b4.y, b4.z, b4.w};
#pragma unroll
      for (int i = 0; i < 4; ++i)
#pragma unroll
        for (int j = 0; j < 4; ++j) acc[i][j] = fmaf(av[i], bv[j], acc[i][j]);
    }
  }
  int c0 = n0 + tx*4;
  int which = c0 / Cn;
  int rem = c0 - which*Cn;
  int h = rem >> 6, dd = rem & 63;
  float* dst = which == 0 ? qb : (which == 1 ? kb : vb);
  float sc = which == 0 ? 0.125f : 1.0f;   // q pre-scaled by d^-0.5
  float4 bsv = *(const float4*)(bias + c0);
#pragma unroll
  for (int i = 0; i < 4; ++i) {
    int m = m0 + ty*4 + i;
    int bbi = m >> 10, n = m & 1023;
    float4 o;
    o.x = (acc[i][0] + bsv.x) * sc;
    o.y = (acc[i][1] + bsv.y) * sc;
    o.z = (acc[i][2] + bsv.z) * sc;
    o.w = (acc[i][3] + bsv.w) * sc;
    *(float4*)(dst + (((size_t)(bbi*Hn + h))*Nn + n)*Dn + dd) = o;
  }
}

// ---------------- Proj GEMM: out = att @ proj_w^T + b -----------------------
__global__ __launch_bounds__(256) void proj_gemm(
    const float* __restrict__ X, const float* __restrict__ Wm,
    const float* __restrict__ bias, float* __restrict__ Out)
{
  constexpr int K = Cn, BK = 16, PAD = 68;
  __shared__ float As[BK][PAD];
  __shared__ float Bs[BK][PAD];
  int t = threadIdx.x;
  int tx = t & 15, ty = t >> 4;
  int mt = blockIdx.x & 127;
  int nt = blockIdx.x >> 7;         // 12 n-tiles
  int m0 = mt * 64, n0 = nt * 64;
  int lrow = t >> 2;
  int lk = (t & 3) * 4;
  const float* Arow = X + (size_t)(m0 + lrow) * K + lk;
  const float* Brow = Wm + (size_t)(n0 + lrow) * K + lk;
  float acc[4][4] = {};
  for (int k0 = 0; k0 < K; k0 += BK) {
    float4 a = *(const float4*)(Arow + k0);
    float4 b = *(const float4*)(Brow + k0);
    __syncthreads();
    As[lk+0][lrow] = a.x; As[lk+1][lrow] = a.y; As[lk+2][lrow] = a.z; As[lk+3][lrow] = a.w;
    Bs[lk+0][lrow] = b.x; Bs[lk+1][lrow] = b.y; Bs[lk+2][lrow] = b.z; Bs[lk+3][lrow] = b.w;
    __syncthreads();
#pragma unroll
    for (int kk = 0; kk < BK; ++kk) {
      float4 a4 = *(const float4*)(&As[kk][ty*4]);
      float4 b4 = *(const float4*)(&Bs[kk][tx*4]);
      float av[4] = {a4.x, a4.y, a4.z, a4.w};
      float bv[4] = {b4.x, b4.y, b4.z, b4.w};
#pragma unroll
      for (int i = 0; i < 4; ++i)
#pragma unroll
        for (int j = 0; j < 4; ++j) acc[i][j] = fmaf(av[i], bv[j], acc[i][j]);
    }
  }
  int c0 = n0 + tx*4;
  float4 bsv = *(const float4*)(bias + c0);
#pragma unroll
  for (int i = 0; i < 4; ++i) {
    int m = m0 + ty*4 + i;
    float4 o;
    o.x = acc[i][0] + bsv.x;
    o.y = acc[i][1] + bsv.y;
    o.z = acc[i][2] + bsv.z;
    o.w = acc[i][3] + bsv.w;
    *(float4*)(Out + (size_t)m*Cn + c0) = o;
  }
}

// ---------------- Attention: scores + ballot-bisect exact top-k + softmax + PV
// One block = (b,h) x 8 q-rows, 512 threads = 8 waves; wave w owns row w.
__global__ __launch_bounds__(512, 4) void attn_kernel(
    const float* __restrict__ qB, const float* __restrict__ kB,
    const float* __restrict__ vB, const int* __restrict__ kptr,
    float* __restrict__ out)
{
  constexpr int G = 8, CAP = 160;
  __shared__ float  Ws[G][1024];     // scores -> (fallback weights), 32 KB
  __shared__ float4 Qs[G][16];       // 2 KB
  __shared__ float2 PairS[G][CAP];   // (weight, idx-as-bits) packed, 10 KB

  int t = threadIdx.x;
  int bh = blockIdx.x >> 7;          // 0..95  (b*12+h)
  int qg = blockIdx.x & 127;
  int qbase = qg * G;
  const float* Kbh = kB + (size_t)bh * Nn * Dn;
  const float* Vbh = vB + (size_t)bh * Nn * Dn;
  const float* Qbh = qB + (size_t)bh * Nn * Dn;

  // stage Q rows (q already scaled by 1/8)
  for (int i = t; i < G*16; i += 512) {
    int r = i >> 4, d4 = i & 15;
    Qs[r][d4] = ((const float4*)(Qbh + (size_t)(qbase + r) * Dn))[d4];
  }
  __syncthreads();

  // ---- scores: thread = (key-base, row-half); 4 keys in flight x 4 rows ----
  {
    int th = t & 255;          // key base
    int half = t >> 8;         // 0: rows 0-3, 1: rows 4-7
    int rbase = half * 4;
    const float4* Kp0 = (const float4*)(Kbh + (size_t)(th        ) * Dn);
    const float4* Kp1 = (const float4*)(Kbh + (size_t)(th +  256) * Dn);
    const float4* Kp2 = (const float4*)(Kbh + (size_t)(th +  512) * Dn);
    const float4* Kp3 = (const float4*)(Kbh + (size_t)(th +  768) * Dn);
    float acc[4][4] = {};      // [row'][c]
#pragma unroll
    for (int d4 = 0; d4 < 16; ++d4) {
      float4 kx0 = Kp0[d4], kx1 = Kp1[d4], kx2 = Kp2[d4], kx3 = Kp3[d4];
#pragma unroll
      for (int rr = 0; rr < 4; ++rr) {
        float4 q4 = Qs[rbase + rr][d4];   // uniform LDS read -> broadcast
        // keep fma chain order identical to R1/R2 (bit-identical scores)
        acc[rr][0] = fmaf(q4.x,kx0.x, fmaf(q4.y,kx0.y, fmaf(q4.z,kx0.z, fmaf(q4.w,kx0.w, acc[rr][0]))));
        acc[rr][1] = fmaf(q4.x,kx1.x, fmaf(q4.y,kx1.y, fmaf(q4.z,kx1.z, fmaf(q4.w,kx1.w, acc[rr][1]))));
        acc[rr][2] = fmaf(q4.x,kx2.x, fmaf(q4.y,kx2.y, fmaf(q4.z,kx2.z, fmaf(q4.w,kx2.w, acc[rr][2]))));
        acc[rr][3] = fmaf(q4.x,kx3.x, fmaf(q4.y,kx3.y, fmaf(q4.z,kx3.z, fmaf(q4.w,kx3.w, acc[rr][3]))));
      }
    }
#pragma unroll
    for (int rr = 0; rr < 4; ++rr) {
      Ws[rbase+rr][th      ] = acc[rr][0];
      Ws[rbase+rr][th +  256] = acc[rr][1];
      Ws[rbase+rr][th +  512] = acc[rr][2];
      Ws[rbase+rr][th +  768] = acc[rr][3];
    }
  }
  __syncthreads();

  // ---- wave-private: row w, 16 scores per lane (j = lane + 64*i) ----
  int w = t >> 6, lane = t & 63;
  float f[16];
  unsigned u[16];
#pragma unroll
  for (int i = 0; i < 16; ++i) {
    f[i] = Ws[w][lane + 64*i];     // stride-64: 2-way bank alias (free)
    u[i] = toOrd(f[i]);
  }

  // row max (for softmax)
  float m = f[0];
#pragma unroll
  for (int i = 1; i < 16; ++i) m = fmaxf(m, f[i]);
#pragma unroll
  for (int off = 32; off; off >>= 1) m = fmaxf(m, __shfl_xor(m, off));

  // ---- exact k-th largest: 32-step bisection, ballot-counted (no shuffles) --
  int kval = *kptr;                       // uniform -> s_load
  bool doSel = (kval > 0 && kval < Nn);   // uniform
  unsigned thr = 0u;                      // thr=0 keeps everything
  if (doSel) {
    unsigned res = 0u;
    for (int b = 31; b >= 0; --b) {
      unsigned cand = res | (1u << b);
      int c = 0;
#pragma unroll
      for (int i = 0; i < 16; ++i)
        c += __popcll(__ballot(u[i] >= cand));   // v_cmp + s_bcnt1: scalar sum
      if (c >= kval) res = cand;          // uniform update
    }
    thr = res;   // exact bit pattern of the k-th largest score
  }

  // ---- weights + ballot compaction + Z ----
  float Zl = 0.f;
  int cnt = 0;
#pragma unroll
  for (int i = 0; i < 16; ++i) {
    bool keep = (u[i] >= thr);
    unsigned long long msk = __ballot(keep);
    float wgt = 0.f;
    if (keep) {
      wgt = __expf(f[i] - m);
      Zl += wgt;                        // Z over ALL survivors (CAP-independent)
      int pos = cnt + __popcll(msk & ((1ull << lane) - 1ull));
      if (pos < CAP) {
        float2 p; p.x = wgt; p.y = __int_as_float(lane + 64*i);
        PairS[w][pos] = p;
      }
    }
    Ws[w][lane + 64*i] = wgt;           // only consumed by rare fallback path
    cnt += __popcll(msk);
  }
#pragma unroll
  for (int off = 32; off; off >>= 1) Zl += __shfl_xor(Zl, off);
  __syncthreads();   // make wave-local LDS writes visible

  // ---- PV: lane = output dim, survivors broadcast from LDS ----
  float acc = 0.f;
  if (cnt <= CAP) {
    int i = 0;
    for (; i + 4 <= cnt; i += 4) {
      float2 p0 = PairS[w][i],   p1 = PairS[w][i+1];
      float2 p2 = PairS[w][i+2], p3 = PairS[w][i+3];
      int j0 = __float_as_int(p0.y), j1 = __float_as_int(p1.y);
      int j2 = __float_as_int(p2.y), j3 = __float_as_int(p3.y);
      float v0 = Vbh[(size_t)j0*Dn + lane];
      float v1 = Vbh[(size_t)j1*Dn + lane];
      float v2 = Vbh[(size_t)j2*Dn + lane];
      float v3 = Vbh[(size_t)j3*Dn + lane];
      acc = fmaf(p0.x, v0, acc);
      acc = fmaf(p1.x, v1, acc);
      acc = fmaf(p2.x, v2, acc);
      acc = fmaf(p3.x, v3, acc);
    }
    for (; i < cnt; ++i) {
      float2 p = PairS[w][i];
      acc = fmaf(p.x, Vbh[(size_t)__float_as_int(p.y)*Dn + lane], acc);
    }
  } else {  // tie overflow fallback (rare): walk all keys
    for (int j = 0; j < 1024; ++j) {
      float wgt = Ws[w][j];
      if (wgt != 0.f) acc = fmaf(wgt, Vbh[(size_t)j*Dn + lane], acc);
    }
  }

  int b = bh / Hn, h = bh - b*Hn;
  out[((size_t)(b*Nn + qbase + w))*Cn + h*Dn + lane] = acc * (1.0f / Zl);
}

extern "C" void kernel_launch(void* const* d_in, const int* in_sizes, int n_in,
                              void* d_out, int out_size, void* d_ws, size_t ws_size,
                              hipStream_t stream) {
  const float* x      = (const float*)d_in[0];
  const float* qkv_w  = (const float*)d_in[1];
  const float* qkv_b  = (const float*)d_in[2];
  const float* proj_w = (const float*)d_in[3];
  const float* proj_b = (const float*)d_in[4];
  const int*   kptr   = (const int*)d_in[5];

  float* ws  = (float*)d_ws;
  const size_t sz = (size_t)Bn * Hn * Nn * Dn;   // 6291456 elements
  float* qbuf = ws;
  float* kbuf = ws + sz;
  float* vbuf = ws + 2*sz;
  float* att  = ws + 3*sz;                       // (B,N,C)
  float* outp = (float*)d_out;

  qkv_gemm<<<dim3(36*128), 256, 0, stream>>>(x, qkv_w, qkv_b, qbuf, kbuf, vbuf);
  attn_kernel<<<dim3(Bn*Hn*(Nn/8)), 512, 0, stream>>>(qbuf, kbuf, vbuf, kptr, att);
  proj_gemm<<<dim3(12*128), 256, 0, stream>>>(att, proj_w, proj_b, outp);
}